// Round 12
// baseline (204.299 us; speedup 1.0000x reference)
//
#include <hip/hip_runtime.h>
#include <hip/hip_bf16.h>

#define NN 384
#define DD 128
#define MM (NN*NN)   // 147456 rows
#define IDJ 49152    // i-stride of mid[i][jb12][d128][jt32] (12*4096)

typedef __attribute__((ext_vector_type(8))) short short8;
typedef __attribute__((ext_vector_type(4))) float f32x4;

__device__ __forceinline__ unsigned short f2bf(float f){
  unsigned u = __float_as_uint(f);
  u += 0x7fffu + ((u >> 16) & 1u);      // RNE
  return (unsigned short)(u >> 16);
}
__device__ __forceinline__ float bf2f(unsigned short u){
  return __uint_as_float(((unsigned)u) << 16);
}
__device__ __forceinline__ float sigm(float x){
  return 1.0f / (1.0f + __expf(-x));
}
__device__ __forceinline__ unsigned cvtpk(float lo, float hi){
  unsigned r;
  asm("v_cvt_pk_bf16_f32 %0, %1, %2" : "=v"(r) : "v"(lo), "v"(hi));
  return r;
}
__device__ __forceinline__ f32x4 mfma16(short8 a, short8 b, f32x4 c){
  return __builtin_amdgcn_mfma_f32_16x16x32_bf16(a, b, c, 0, 0, 0);
}
// async global->LDS, 16B/lane; LDS base wave-uniform (HW adds lane*16)
__device__ __forceinline__ void gll16(const void* g, void* l){
  __builtin_amdgcn_global_load_lds(
      (const __attribute__((address_space(1))) unsigned int*)g,
      (__attribute__((address_space(3))) unsigned int*)l, 16, 0, 0);
}

// ---------------------------------------------------------------------------
// k_prep: Wcat_t[n][k] bf16 = [Wl|Wlg|Wr|Wrg|Wog]^T (n in [0,640)); Wot = Wo^T.
__global__ void k_prep(const float* __restrict__ Wl, const float* __restrict__ Wlg,
                       const float* __restrict__ Wr, const float* __restrict__ Wrg,
                       const float* __restrict__ Wog, const float* __restrict__ Wo,
                       unsigned short* __restrict__ Wcat, unsigned short* __restrict__ Wot){
  int n = blockIdx.x;           // 0..767
  if(n < 640){
    const float* src; int col;
    if(n < 128){ src = Wl;  col = n; }
    else if(n < 256){ src = Wlg; col = n-128; }
    else if(n < 384){ src = Wr;  col = n-256; }
    else if(n < 512){ src = Wrg; col = n-384; }
    else            { src = Wog; col = n-512; }
    for(int k = threadIdx.x; k < 128; k += 64)
      Wcat[n*128 + k] = f2bf(src[k*128 + col]);
  } else {
    int c = n - 640;
    for(int k = threadIdx.x; k < 128; k += 64)
      Wot[c*128 + k] = f2bf(Wo[k*128 + c]);
  }
}

// ---------------------------------------------------------------------------
// k_lng: fused LayerNorm(x) -> xn  AND  gate = sigm(xn @ Wog + bog).
__global__ __launch_bounds__(256, 3) void k_lng(
    const float* __restrict__ x, const float* __restrict__ na,
    const float* __restrict__ nb, const unsigned short* __restrict__ Wcat,
    const float* __restrict__ bog,
    unsigned short* __restrict__ xn, unsigned short* __restrict__ gate){
  __shared__ char lds[32768];            // xn tile [128 rows][256B], swizzled
  const int tid = threadIdx.x;
  const int wid = tid >> 6, lane = tid & 63;
  const int lrow = lane & 15, lgrp = lane >> 4;
  const long m0 = (long)blockIdx.x * 128;

  float2 a2 = *(const float2*)(na + lane*2);
  float2 b2 = *(const float2*)(nb + lane*2);

  #pragma unroll 2
  for(int b4 = 0; b4 < 8; ++b4){
    float2 v[4];
    #pragma unroll
    for(int s = 0; s < 4; ++s)
      v[s] = *(const float2*)(x + (m0 + wid*32 + b4*4 + s)*DD + lane*2);
    #pragma unroll
    for(int s = 0; s < 4; ++s){
      int r = wid*32 + b4*4 + s;
      float sm = v[s].x + v[s].y, sq = v[s].x*v[s].x + v[s].y*v[s].y;
      #pragma unroll
      for(int m = 32; m >= 1; m >>= 1){ sm += __shfl_xor(sm,m); sq += __shfl_xor(sq,m); }
      float mean = sm*(1.f/128.f);
      float var  = sq*(1.f/128.f) - mean*mean;
      float rstd = rsqrtf(var + 1e-5f);
      unsigned pk = cvtpk(a2.x*(v[s].x-mean)*rstd + b2.x,
                          a2.y*(v[s].y-mean)*rstd + b2.y);
      *(unsigned*)(xn + (m0+r)*DD + lane*2) = pk;
      *(unsigned*)(&lds[r*256 + ((lane*4) ^ ((r&7)<<4))]) = pk;
    }
  }
  __syncthreads();

  // gate MFMA: wave wid owns 32 c-cols
  f32x4 acc[2][8];                       // [cf][mf]
  #pragma unroll
  for(int cf = 0; cf < 2; ++cf){
    int c0 = wid*32 + cf*16 + lgrp*4;
    float4 b4v = *(const float4*)(bog + c0);
    #pragma unroll
    for(int mf = 0; mf < 8; ++mf) acc[cf][mf] = (f32x4){b4v.x,b4v.y,b4v.z,b4v.w};
  }
  #pragma unroll
  for(int ks = 0; ks < 4; ++ks){
    short8 af0 = *(const short8*)(Wcat + (512 + wid*32 + lrow)*DD + ks*32 + lgrp*8);
    short8 af1 = *(const short8*)(Wcat + (512 + wid*32 + 16 + lrow)*DD + ks*32 + lgrp*8);
    #pragma unroll
    for(int mf = 0; mf < 8; ++mf){
      int r = mf*16 + lrow;
      short8 bx = *(const short8*)(&lds[r*256 + (((ks*4+lgrp)*16) ^ ((r&7)<<4))]);
      acc[0][mf] = mfma16(af0, bx, acc[0][mf]);
      acc[1][mf] = mfma16(af1, bx, acc[1][mf]);
    }
  }
  // packed 8B stores, pre-swizzled within the 256B row
  #pragma unroll
  for(int cf = 0; cf < 2; ++cf){
    int c0 = wid*32 + cf*16 + lgrp*4;
    #pragma unroll
    for(int mf = 0; mf < 8; ++mf){
      int rr = mf*16 + lrow;
      uint2 pk;
      pk.x = cvtpk(sigm(acc[cf][mf][0]), sigm(acc[cf][mf][1]));
      pk.y = cvtpk(sigm(acc[cf][mf][2]), sigm(acc[cf][mf][3]));
      *(uint2*)((char*)gate + (m0+rr)*256 + ((c0*2) ^ ((rr&7)<<4))) = pk;
    }
  }
}

// ---------------------------------------------------------------------------
// k_proj: persistent L/R projection (unchanged).
__global__ __launch_bounds__(256, 4) void k_proj(
    const unsigned short* __restrict__ xn, const unsigned short* __restrict__ Wcat,
    const float* __restrict__ bl, const float* __restrict__ blg,
    const float* __restrict__ br, const float* __restrict__ brg,
    unsigned short* __restrict__ Lt, unsigned short* __restrict__ Rt){
  __shared__ char lds[2][16384];
  const int tid = threadIdx.x;
  const int wid = tid >> 6, lane = tid & 63;
  const int lrow = lane & 15, lgrp = lane >> 4;
  const int b = blockIdx.x;            // 1152 = 4*288
  const int f = b / 288;               // d-quarter
  const int w = b % 288;

  const int ws = wid >> 1;             // 0=L 1=R
  const int wd = wid & 1;              // d-16-half of quarter
  const int d  = f*32 + wd*16 + lrow;

  short8 bv[4], bg[4];
  #pragma unroll
  for(int ks = 0; ks < 4; ++ks){
    bv[ks] = *(const short8*)(Wcat + (ws*256 + d)*DD + ks*32 + lgrp*8);
    bg[ks] = *(const short8*)(Wcat + (ws*256 + 128 + d)*DD + ks*32 + lgrp*8);
  }
  const float b0v = (ws ? br  : bl )[d];
  const float b1v = (ws ? brg : blg)[d];
  const float sc  = ws ? 1.0f : (1.0f/384.0f);   // fold einsum 1/n into Lt
  unsigned short* const base = (ws ? Rt : Lt) + (long)d*MM;

  auto stage = [&](int buf, int v){
    int j = v/6, kb = v%6;
    int rsub = lane >> 4, c = lane & 15;
    #pragma unroll
    for(int p = 0; p < 4; ++p){
      int r0 = p*16 + wid*4;
      int r = r0 + rsub;
      gll16(xn + ((long)(kb*64 + r)*NN + j)*DD + (c ^ (r & 7))*8, &lds[buf][r0*256]);
    }
  };

  stage(0, w*8);
  __syncthreads();
  int cur = 0;
  for(int i = 0; i < 8; ++i){
    int v = w*8 + i;
    if(i < 7) stage(cur^1, v+1);       // prefetch flies over compute+epilogue

    f32x4 zero = {0.f,0.f,0.f,0.f};
    f32x4 acc[4][2];
    #pragma unroll
    for(int a1=0;a1<4;++a1){ acc[a1][0] = zero; acc[a1][1] = zero; }

    #pragma unroll
    for(int ks = 0; ks < 4; ++ks){
      #pragma unroll
      for(int fr = 0; fr < 4; ++fr){
        int r = fr*16 + lrow;
        short8 af = *(const short8*)(&lds[cur][r*256 + (((ks*4+lgrp)*16) ^ ((r&7)<<4))]);
        acc[fr][0] = mfma16(af, bv[ks], acc[fr][0]);
        acc[fr][1] = mfma16(af, bg[ks], acc[fr][1]);
      }
    }

    int j = v/6, kb = v%6;
    unsigned short* dst = base + (long)j*NN + kb*64;
    #pragma unroll
    for(int fr = 0; fr < 4; ++fr){
      float v0 = (acc[fr][0][0] + b0v)*sigm(acc[fr][1][0] + b1v)*sc;
      float v1 = (acc[fr][0][1] + b0v)*sigm(acc[fr][1][1] + b1v)*sc;
      float v2 = (acc[fr][0][2] + b0v)*sigm(acc[fr][1][2] + b1v)*sc;
      float v3 = (acc[fr][0][3] + b0v)*sigm(acc[fr][1][3] + b1v)*sc;
      uint2 pk; pk.x = cvtpk(v0, v1); pk.y = cvtpk(v2, v3);
      *(uint2*)(dst + fr*16 + lgrp*4) = pk;
    }
    __syncthreads();                   // prefetch landed; buffers swap
    cur ^= 1;
  }
}

// ---------------------------------------------------------------------------
// k_einsum: per d: mid[i][jb][d][jt] = sum_k Rt[d][i][k]*Lt[d][j][k] (1/384 in
//  Lt), jb = j/32, jt = j%32.  k_final's 64-j strip is then one CONTIGUOUS
//  16KB region (full DRAM row utilization); each 64B line (i,jb,d) is fully
//  owned by one einsum block (clean write-combining).
__global__ __launch_bounds__(256) void k_einsum(
    const unsigned short* __restrict__ Rt, const unsigned short* __restrict__ Lt,
    unsigned short* __restrict__ mid){
  __shared__ char lds[65536];
  const int b = blockIdx.x;              // 1152 = 8 * 144
  const int xcd = b & 7, slot = b >> 3;
  const int d = (slot/9)*8 + xcd;
  const int t = slot % 9;
  const int it = t/3, jt = t%3;
  const int i0 = it*128, j0 = jt*128;
  const unsigned short* Abase = Lt + (long)d*MM;   // j-rows
  const unsigned short* Bbase = Rt + (long)d*MM;   // i-rows
  const int wid = threadIdx.x >> 6, lane = threadIdx.x & 63;
  const int wr = wid >> 1, wc = wid & 1;
  const int lrow = lane & 15, lgrp = lane >> 4;

  auto stage = [&](int buf, int kt){
    int k = kt*64;
    int c = lane & 7;
    #pragma unroll
    for(int t8 = 0; t8 < 8; ++t8){
      int rr = wid*64 + t8*8 + (lane >> 3);   // 0..255 (first 128 = A rows)
      int r = rr & 127;
      const unsigned short* src = (rr < 128) ? (Abase + (long)(j0+r)*NN + k)
                                             : (Bbase + (long)(i0+r)*NN + k);
      gll16(src + (c ^ (r & 7))*8, &lds[buf*32768 + (wid*64 + t8*8)*128]);
    }
  };

  f32x4 zero = {0.f,0.f,0.f,0.f};
  f32x4 acc[4][4];                       // [fj][fi]
  #pragma unroll
  for(int a1 = 0; a1 < 4; ++a1)
    #pragma unroll
    for(int a2 = 0; a2 < 4; ++a2) acc[a1][a2] = zero;

  stage(0, 0);
  __syncthreads();
  for(int kt = 0; kt < 6; ++kt){
    int cur = kt & 1;
    if(kt < 5) stage(cur ^ 1, kt + 1);
    const int base = cur*32768;
    #pragma unroll
    for(int ks = 0; ks < 2; ++ks){
      short8 af[4], bf[4];
      #pragma unroll
      for(int f = 0; f < 4; ++f){
        int rj = wr*64 + f*16 + lrow;
        af[f] = *(const short8*)(&lds[base + rj*128 + (((ks*4+lgrp)*16) ^ ((rj & 7) << 4))]);
        int ri = wc*64 + f*16 + lrow;
        bf[f] = *(const short8*)(&lds[base + 16384 + ri*128 + (((ks*4+lgrp)*16) ^ ((ri & 7) << 4))]);
      }
      #pragma unroll
      for(int fj = 0; fj < 4; ++fj)
        #pragma unroll
        for(int fi = 0; fi < 4; ++fi)
          acc[fj][fi] = mfma16(af[fj], bf[fi], acc[fj][fi]);
    }
    __syncthreads();
  }

  #pragma unroll
  for(int fj = 0; fj < 4; ++fj){
    int j = j0 + wr*64 + fj*16 + lgrp*4;
    #pragma unroll
    for(int fi = 0; fi < 4; ++fi){
      int i = i0 + wc*64 + fi*16 + lrow;
      uint2 pk;
      pk.x = cvtpk(acc[fj][fi][0], acc[fj][fi][1]);
      pk.y = cvtpk(acc[fj][fi][2], acc[fj][fi][3]);
      *(uint2*)(mid + (long)i*IDJ + ((j>>5)<<12) + (d<<5) + (j&31)) = pk;
    }
  }
}

// ---------------------------------------------------------------------------
// k_final v8: per (i, 64-j strip). mid strip = ONE contiguous 16KB region
//  (layout [i][jb][d][jt32]) staged linearly via gll16 -> M. Gate strip
//  staged (pre-swizzled) -> G. LN over d via u16 LDS reads (64B stride,
//  ~4-way conflicts, negligible); val overwrites G in place; out MFMA.
__global__ __launch_bounds__(256, 4) void k_final(
    const unsigned short* __restrict__ mid, const unsigned short* __restrict__ gate,
    const float* __restrict__ ona, const float* __restrict__ onb,
    const unsigned short* __restrict__ Wot, const float* __restrict__ bo,
    float* __restrict__ out){
  __shared__ char M[16384];                  // mid strip [jb2][d128][jt32]
  __shared__ char G[16384];                  // gate -> val (in place)
  const int tid = threadIdx.x;
  const int wid = tid >> 6, lane = tid & 63;
  const int lrow = lane & 15, lgrp = lane >> 4;
  const int b = blockIdx.x;
  const int xcd = b & 7, slot = b >> 3;      // 2304 = 8*288
  const int i = xcd + (slot/6)*8;
  const int j0 = (slot%6)*64;

  { // stage mid strip: 16KB CONTIGUOUS
    const char* msrc = (const char*)mid + (long)i*98304 + (j0>>5)*8192;
    #pragma unroll
    for(int p = 0; p < 4; ++p)
      gll16(msrc + p*4096 + wid*1024 + lane*16, &M[p*4096 + wid*1024]);
  }
  { // stage gate strip: 16KB contiguous (content pre-swizzled by k_lng)
    const char* gsrc = (const char*)gate + ((long)i*NN + j0)*256;
    #pragma unroll
    for(int p = 0; p < 4; ++p)
      gll16(gsrc + p*4096 + wid*1024 + lane*16, &G[p*4096 + wid*1024]);
  }
  __syncthreads();                           // B1: M + G ready

  { // LN + gate-mul, 4 threads per j-row (32 d each); val -> G in place
    int j = tid >> 2, s = tid & 3;
    const int mrow = (j >> 5)*8192 + (j & 31)*2;   // byte base in M
    float sum = 0.f, sq = 0.f;
    #pragma unroll
    for(int o = 0; o < 32; ++o){
      int d = s*32 + o;
      float v = bf2f(*(const unsigned short*)(&M[mrow + d*64]));
      sum += v; sq += v*v;
    }
    sum += __shfl_xor(sum, 1); sq += __shfl_xor(sq, 1);
    sum += __shfl_xor(sum, 2); sq += __shfl_xor(sq, 2);
    float mean = sum*(1.f/128.f);
    float var  = sq *(1.f/128.f) - mean*mean;
    float rstd = rsqrtf(var + 1e-5f);
    #pragma unroll
    for(int o = 0; o < 32; o += 4){
      int dd = s*32 + o;
      float m0 = bf2f(*(const unsigned short*)(&M[mrow + (dd+0)*64]));
      float m1 = bf2f(*(const unsigned short*)(&M[mrow + (dd+1)*64]));
      float m2 = bf2f(*(const unsigned short*)(&M[mrow + (dd+2)*64]));
      float m3 = bf2f(*(const unsigned short*)(&M[mrow + (dd+3)*64]));
      char* gp = &G[j*256 + ((dd*2) ^ ((j&7)<<4))];
      uint2 gvv = *(uint2*)gp;
      float g0 = bf2f((unsigned short)(gvv.x & 0xffffu));
      float g1 = bf2f((unsigned short)(gvv.x >> 16));
      float g2 = bf2f((unsigned short)(gvv.y & 0xffffu));
      float g3 = bf2f((unsigned short)(gvv.y >> 16));
      float4 a4 = *(const float4*)(ona + dd);
      float4 b4 = *(const float4*)(onb + dd);
      float v0 = (a4.x*(m0-mean)*rstd + b4.x)*g0;
      float v1 = (a4.y*(m1-mean)*rstd + b4.y)*g1;
      float v2 = (a4.z*(m2-mean)*rstd + b4.z)*g2;
      float v3 = (a4.w*(m3-mean)*rstd + b4.w)*g3;
      uint2 pk; pk.x = cvtpk(v0, v1); pk.y = cvtpk(v2, v3);
      *(uint2*)gp = pk;                      // same thread RW: safe
    }
  }
  __syncthreads();                           // B2: val ready

  { // out MFMA: each wave = 16 j-rows x all 128 c; 4B stores, 64B segments
    f32x4 zero = {0.f,0.f,0.f,0.f};
    f32x4 acc[8];
    #pragma unroll
    for(int fc = 0; fc < 8; ++fc) acc[fc] = zero;
    #pragma unroll 1
    for(int ks = 0; ks < 4; ++ks){
      int row = wid*16 + lrow;
      short8 a = *(const short8*)(&G[row*256 + (((ks*4+lgrp)*16) ^ ((row & 7) << 4))]);
      #pragma unroll
      for(int fc = 0; fc < 8; ++fc){
        short8 bfr = *(const short8*)(Wot + (fc*16 + lrow)*DD + ks*32 + lgrp*8);
        acc[fc] = mfma16(a, bfr, acc[fc]);
      }
    }
    #pragma unroll
    for(int fc = 0; fc < 8; ++fc){
      int c = fc*16 + lrow;
      float bb = bo[c];
      #pragma unroll
      for(int q = 0; q < 4; ++q){
        int jl = wid*16 + lgrp*4 + q;
        out[((long)i*NN + j0 + jl)*DD + c] = acc[fc][q] + bb;
      }
    }
  }
}

// ---------------------------------------------------------------------------
extern "C" void kernel_launch(void* const* d_in, const int* in_sizes, int n_in,
                              void* d_out, int out_size, void* d_ws, size_t ws_size,
                              hipStream_t stream){
  const float* x   = (const float*)d_in[0];
  const float* na  = (const float*)d_in[1];
  const float* nb  = (const float*)d_in[2];
  const float* Wl  = (const float*)d_in[3];
  const float* bl  = (const float*)d_in[4];
  const float* Wr  = (const float*)d_in[5];
  const float* br  = (const float*)d_in[6];
  const float* Wlg = (const float*)d_in[7];
  const float* blg = (const float*)d_in[8];
  const float* Wrg = (const float*)d_in[9];
  const float* brg = (const float*)d_in[10];
  const float* Wog = (const float*)d_in[11];
  const float* bog = (const float*)d_in[12];
  const float* ona = (const float*)d_in[13];
  const float* onb = (const float*)d_in[14];
  const float* Wo  = (const float*)d_in[15];
  const float* bo  = (const float*)d_in[16];
  float* out = (float*)d_out;

  char* ws = (char*)d_ws;
  const size_t SZ = (size_t)MM*DD*2;                    // 37.75 MB
  unsigned short* xn   = (unsigned short*)(ws);         // dead after k_proj
  unsigned short* Lt   = (unsigned short*)(ws + SZ);
  unsigned short* Rt   = (unsigned short*)(ws + 2*SZ);
  unsigned short* gate = (unsigned short*)(ws + 3*SZ);  // k_lng -> k_final
  unsigned short* Wcat = (unsigned short*)(ws + 4*SZ);
  unsigned short* Wot  = (unsigned short*)(ws + 4*SZ + (size_t)640*128*2);
  unsigned short* mid  = xn;                            // overlay (xn dead)

  k_prep  <<<768, 64, 0, stream>>>(Wl, Wlg, Wr, Wrg, Wog, Wo, Wcat, Wot);
  k_lng   <<<1152, 256, 0, stream>>>(x, na, nb, Wcat, bog, xn, gate);
  k_proj  <<<1152, 256, 0, stream>>>(xn, Wcat, bl, blg, br, brg, Lt, Rt);
  k_einsum<<<1152, 256, 0, stream>>>(Rt, Lt, mid);
  k_final <<<2304, 256, 0, stream>>>(mid, gate, ona, onb, Wot, bo, out);
}

// Round 13
// 186.048 us; speedup vs baseline: 1.0981x; 1.0981x over previous
//
#include <hip/hip_runtime.h>
#include <hip/hip_bf16.h>

#define NN 384
#define DD 128
#define MM (NN*NN)   // 147456 rows
#define IDJ 49152    // i-stride of mid[i][jb12][d128][jt32] (12*4096)

typedef __attribute__((ext_vector_type(8))) short short8;
typedef __attribute__((ext_vector_type(4))) float f32x4;

__device__ __forceinline__ unsigned short f2bf(float f){
  unsigned u = __float_as_uint(f);
  u += 0x7fffu + ((u >> 16) & 1u);      // RNE
  return (unsigned short)(u >> 16);
}
__device__ __forceinline__ float bf2f(unsigned short u){
  return __uint_as_float(((unsigned)u) << 16);
}
__device__ __forceinline__ float sigm(float x){
  return 1.0f / (1.0f + __expf(-x));
}
__device__ __forceinline__ unsigned cvtpk(float lo, float hi){
  unsigned r;
  asm("v_cvt_pk_bf16_f32 %0, %1, %2" : "=v"(r) : "v"(lo), "v"(hi));
  return r;
}
__device__ __forceinline__ f32x4 mfma16(short8 a, short8 b, f32x4 c){
  return __builtin_amdgcn_mfma_f32_16x16x32_bf16(a, b, c, 0, 0, 0);
}
// async global->LDS, 16B/lane; LDS base wave-uniform (HW adds lane*16)
__device__ __forceinline__ void gll16(const void* g, void* l){
  __builtin_amdgcn_global_load_lds(
      (const __attribute__((address_space(1))) unsigned int*)g,
      (__attribute__((address_space(3))) unsigned int*)l, 16, 0, 0);
}

// ---------------------------------------------------------------------------
// k_prep: Wcat_t[n][k] bf16 = [Wl|Wlg|Wr|Wrg|Wog]^T (n in [0,640)); Wot = Wo^T.
__global__ void k_prep(const float* __restrict__ Wl, const float* __restrict__ Wlg,
                       const float* __restrict__ Wr, const float* __restrict__ Wrg,
                       const float* __restrict__ Wog, const float* __restrict__ Wo,
                       unsigned short* __restrict__ Wcat, unsigned short* __restrict__ Wot){
  int n = blockIdx.x;           // 0..767
  if(n < 640){
    const float* src; int col;
    if(n < 128){ src = Wl;  col = n; }
    else if(n < 256){ src = Wlg; col = n-128; }
    else if(n < 384){ src = Wr;  col = n-256; }
    else if(n < 512){ src = Wrg; col = n-384; }
    else            { src = Wog; col = n-512; }
    for(int k = threadIdx.x; k < 128; k += 64)
      Wcat[n*128 + k] = f2bf(src[k*128 + col]);
  } else {
    int c = n - 640;
    for(int k = threadIdx.x; k < 128; k += 64)
      Wot[c*128 + k] = f2bf(Wo[k*128 + c]);
  }
}

// ---------------------------------------------------------------------------
// k_lng: fused LayerNorm(x) -> xn  AND  gate = sigm(xn @ Wog + bog).
//  64-row tiles, 2304 blocks, 16KB LDS -> 6 blocks/CU (decorrelated bursts).
__global__ __launch_bounds__(256, 6) void k_lng(
    const float* __restrict__ x, const float* __restrict__ na,
    const float* __restrict__ nb, const unsigned short* __restrict__ Wcat,
    const float* __restrict__ bog,
    unsigned short* __restrict__ xn, unsigned short* __restrict__ gate){
  __shared__ char lds[16384];            // xn tile [64 rows][256B], swizzled
  const int tid = threadIdx.x;
  const int wid = tid >> 6, lane = tid & 63;
  const int lrow = lane & 15, lgrp = lane >> 4;
  const long m0 = (long)blockIdx.x * 64;

  float2 a2 = *(const float2*)(na + lane*2);
  float2 b2 = *(const float2*)(nb + lane*2);

  #pragma unroll
  for(int b4 = 0; b4 < 4; ++b4){
    float2 v[4];
    #pragma unroll
    for(int s = 0; s < 4; ++s)
      v[s] = *(const float2*)(x + (m0 + wid*16 + b4*4 + s)*DD + lane*2);
    #pragma unroll
    for(int s = 0; s < 4; ++s){
      int r = wid*16 + b4*4 + s;
      float sm = v[s].x + v[s].y, sq = v[s].x*v[s].x + v[s].y*v[s].y;
      #pragma unroll
      for(int m = 32; m >= 1; m >>= 1){ sm += __shfl_xor(sm,m); sq += __shfl_xor(sq,m); }
      float mean = sm*(1.f/128.f);
      float var  = sq*(1.f/128.f) - mean*mean;
      float rstd = rsqrtf(var + 1e-5f);
      unsigned pk = cvtpk(a2.x*(v[s].x-mean)*rstd + b2.x,
                          a2.y*(v[s].y-mean)*rstd + b2.y);
      *(unsigned*)(xn + (m0+r)*DD + lane*2) = pk;
      *(unsigned*)(&lds[r*256 + ((lane*4) ^ ((r&7)<<4))]) = pk;
    }
  }
  __syncthreads();

  // gate MFMA: wave wid owns 32 c-cols x 64 rows
  f32x4 acc[2][4];                       // [cf][mf]
  #pragma unroll
  for(int cf = 0; cf < 2; ++cf){
    int c0 = wid*32 + cf*16 + lgrp*4;
    float4 b4v = *(const float4*)(bog + c0);
    #pragma unroll
    for(int mf = 0; mf < 4; ++mf) acc[cf][mf] = (f32x4){b4v.x,b4v.y,b4v.z,b4v.w};
  }
  #pragma unroll
  for(int ks = 0; ks < 4; ++ks){
    short8 af0 = *(const short8*)(Wcat + (512 + wid*32 + lrow)*DD + ks*32 + lgrp*8);
    short8 af1 = *(const short8*)(Wcat + (512 + wid*32 + 16 + lrow)*DD + ks*32 + lgrp*8);
    #pragma unroll
    for(int mf = 0; mf < 4; ++mf){
      int r = mf*16 + lrow;
      short8 bx = *(const short8*)(&lds[r*256 + (((ks*4+lgrp)*16) ^ ((r&7)<<4))]);
      acc[0][mf] = mfma16(af0, bx, acc[0][mf]);
      acc[1][mf] = mfma16(af1, bx, acc[1][mf]);
    }
  }
  // packed 8B stores, pre-swizzled within the 256B row
  #pragma unroll
  for(int cf = 0; cf < 2; ++cf){
    int c0 = wid*32 + cf*16 + lgrp*4;
    #pragma unroll
    for(int mf = 0; mf < 4; ++mf){
      int rr = mf*16 + lrow;
      uint2 pk;
      pk.x = cvtpk(sigm(acc[cf][mf][0]), sigm(acc[cf][mf][1]));
      pk.y = cvtpk(sigm(acc[cf][mf][2]), sigm(acc[cf][mf][3]));
      *(uint2*)((char*)gate + (m0+rr)*256 + ((c0*2) ^ ((rr&7)<<4))) = pk;
    }
  }
}

// ---------------------------------------------------------------------------
// k_proj: persistent L/R projection (unchanged).
__global__ __launch_bounds__(256, 4) void k_proj(
    const unsigned short* __restrict__ xn, const unsigned short* __restrict__ Wcat,
    const float* __restrict__ bl, const float* __restrict__ blg,
    const float* __restrict__ br, const float* __restrict__ brg,
    unsigned short* __restrict__ Lt, unsigned short* __restrict__ Rt){
  __shared__ char lds[2][16384];
  const int tid = threadIdx.x;
  const int wid = tid >> 6, lane = tid & 63;
  const int lrow = lane & 15, lgrp = lane >> 4;
  const int b = blockIdx.x;            // 1152 = 4*288
  const int f = b / 288;               // d-quarter
  const int w = b % 288;

  const int ws = wid >> 1;             // 0=L 1=R
  const int wd = wid & 1;              // d-16-half of quarter
  const int d  = f*32 + wd*16 + lrow;

  short8 bv[4], bg[4];
  #pragma unroll
  for(int ks = 0; ks < 4; ++ks){
    bv[ks] = *(const short8*)(Wcat + (ws*256 + d)*DD + ks*32 + lgrp*8);
    bg[ks] = *(const short8*)(Wcat + (ws*256 + 128 + d)*DD + ks*32 + lgrp*8);
  }
  const float b0v = (ws ? br  : bl )[d];
  const float b1v = (ws ? brg : blg)[d];
  const float sc  = ws ? 1.0f : (1.0f/384.0f);   // fold einsum 1/n into Lt
  unsigned short* const base = (ws ? Rt : Lt) + (long)d*MM;

  auto stage = [&](int buf, int v){
    int j = v/6, kb = v%6;
    int rsub = lane >> 4, c = lane & 15;
    #pragma unroll
    for(int p = 0; p < 4; ++p){
      int r0 = p*16 + wid*4;
      int r = r0 + rsub;
      gll16(xn + ((long)(kb*64 + r)*NN + j)*DD + (c ^ (r & 7))*8, &lds[buf][r0*256]);
    }
  };

  stage(0, w*8);
  __syncthreads();
  int cur = 0;
  for(int i = 0; i < 8; ++i){
    int v = w*8 + i;
    if(i < 7) stage(cur^1, v+1);       // prefetch flies over compute+epilogue

    f32x4 zero = {0.f,0.f,0.f,0.f};
    f32x4 acc[4][2];
    #pragma unroll
    for(int a1=0;a1<4;++a1){ acc[a1][0] = zero; acc[a1][1] = zero; }

    #pragma unroll
    for(int ks = 0; ks < 4; ++ks){
      #pragma unroll
      for(int fr = 0; fr < 4; ++fr){
        int r = fr*16 + lrow;
        short8 af = *(const short8*)(&lds[cur][r*256 + (((ks*4+lgrp)*16) ^ ((r&7)<<4))]);
        acc[fr][0] = mfma16(af, bv[ks], acc[fr][0]);
        acc[fr][1] = mfma16(af, bg[ks], acc[fr][1]);
      }
    }

    int j = v/6, kb = v%6;
    unsigned short* dst = base + (long)j*NN + kb*64;
    #pragma unroll
    for(int fr = 0; fr < 4; ++fr){
      float v0 = (acc[fr][0][0] + b0v)*sigm(acc[fr][1][0] + b1v)*sc;
      float v1 = (acc[fr][0][1] + b0v)*sigm(acc[fr][1][1] + b1v)*sc;
      float v2 = (acc[fr][0][2] + b0v)*sigm(acc[fr][1][2] + b1v)*sc;
      float v3 = (acc[fr][0][3] + b0v)*sigm(acc[fr][1][3] + b1v)*sc;
      uint2 pk; pk.x = cvtpk(v0, v1); pk.y = cvtpk(v2, v3);
      *(uint2*)(dst + fr*16 + lgrp*4) = pk;
    }
    __syncthreads();                   // prefetch landed; buffers swap
    cur ^= 1;
  }
}

// ---------------------------------------------------------------------------
// k_einsum: per d: mid[i][jb][d][jt] = sum_k Rt[d][i][k]*Lt[d][j][k] (1/384 in
//  Lt), jb = j/32, jt = j%32.
__global__ __launch_bounds__(256) void k_einsum(
    const unsigned short* __restrict__ Rt, const unsigned short* __restrict__ Lt,
    unsigned short* __restrict__ mid){
  __shared__ char lds[65536];
  const int b = blockIdx.x;              // 1152 = 8 * 144
  const int xcd = b & 7, slot = b >> 3;
  const int d = (slot/9)*8 + xcd;
  const int t = slot % 9;
  const int it = t/3, jt = t%3;
  const int i0 = it*128, j0 = jt*128;
  const unsigned short* Abase = Lt + (long)d*MM;   // j-rows
  const unsigned short* Bbase = Rt + (long)d*MM;   // i-rows
  const int wid = threadIdx.x >> 6, lane = threadIdx.x & 63;
  const int wr = wid >> 1, wc = wid & 1;
  const int lrow = lane & 15, lgrp = lane >> 4;

  auto stage = [&](int buf, int kt){
    int k = kt*64;
    int c = lane & 7;
    #pragma unroll
    for(int t8 = 0; t8 < 8; ++t8){
      int rr = wid*64 + t8*8 + (lane >> 3);   // 0..255 (first 128 = A rows)
      int r = rr & 127;
      const unsigned short* src = (rr < 128) ? (Abase + (long)(j0+r)*NN + k)
                                             : (Bbase + (long)(i0+r)*NN + k);
      gll16(src + (c ^ (r & 7))*8, &lds[buf*32768 + (wid*64 + t8*8)*128]);
    }
  };

  f32x4 zero = {0.f,0.f,0.f,0.f};
  f32x4 acc[4][4];                       // [fj][fi]
  #pragma unroll
  for(int a1 = 0; a1 < 4; ++a1)
    #pragma unroll
    for(int a2 = 0; a2 < 4; ++a2) acc[a1][a2] = zero;

  stage(0, 0);
  __syncthreads();
  for(int kt = 0; kt < 6; ++kt){
    int cur = kt & 1;
    if(kt < 5) stage(cur ^ 1, kt + 1);
    const int base = cur*32768;
    #pragma unroll
    for(int ks = 0; ks < 2; ++ks){
      short8 af[4], bf[4];
      #pragma unroll
      for(int f = 0; f < 4; ++f){
        int rj = wr*64 + f*16 + lrow;
        af[f] = *(const short8*)(&lds[base + rj*128 + (((ks*4+lgrp)*16) ^ ((rj & 7) << 4))]);
        int ri = wc*64 + f*16 + lrow;
        bf[f] = *(const short8*)(&lds[base + 16384 + ri*128 + (((ks*4+lgrp)*16) ^ ((ri & 7) << 4))]);
      }
      #pragma unroll
      for(int fj = 0; fj < 4; ++fj)
        #pragma unroll
        for(int fi = 0; fi < 4; ++fi)
          acc[fj][fi] = mfma16(af[fj], bf[fi], acc[fj][fi]);
    }
    __syncthreads();
  }

  #pragma unroll
  for(int fj = 0; fj < 4; ++fj){
    int j = j0 + wr*64 + fj*16 + lgrp*4;
    #pragma unroll
    for(int fi = 0; fi < 4; ++fi){
      int i = i0 + wc*64 + fi*16 + lrow;
      uint2 pk;
      pk.x = cvtpk(acc[fj][fi][0], acc[fj][fi][1]);
      pk.y = cvtpk(acc[fj][fi][2], acc[fj][fi][3]);
      *(uint2*)(mid + (long)i*IDJ + ((j>>5)<<12) + (d<<5) + (j&31)) = pk;
    }
  }
}

// ---------------------------------------------------------------------------
// k_final v9: 32-j strips, grid 4608 = 8 xcd * 576, 16.5KB LDS -> 8 blocks/CU.
//  M strip = one contiguous 8KB ([d][jt32]); G strip 8KB (pre-swizzled rows).
//  LN keeps the 16 per-thread mid values in REGISTERS (no LDS re-read).
__global__ __launch_bounds__(256, 8) void k_final(
    const unsigned short* __restrict__ mid, const unsigned short* __restrict__ gate,
    const float* __restrict__ ona, const float* __restrict__ onb,
    const unsigned short* __restrict__ Wot, const float* __restrict__ bo,
    float* __restrict__ out){
  __shared__ char M[8192];                   // mid strip [d128][jt32]
  __shared__ char G[8192];                   // gate -> val (in place)
  const int tid = threadIdx.x;
  const int wid = tid >> 6, lane = tid & 63;
  const int lrow = lane & 15, lgrp = lane >> 4;
  const int b = blockIdx.x;
  const int xcd = b & 7, slot = b >> 3;      // 4608 = 8*576
  const int i = xcd + (slot/12)*8;
  const int jb = slot % 12, j0 = jb*32;

  { // stage M: 8KB CONTIGUOUS; G: 8KB contiguous (content pre-swizzled)
    const char* msrc = (const char*)mid + (long)i*98304 + jb*8192;
    const char* gsrc = (const char*)gate + ((long)i*NN + j0)*256;
    #pragma unroll
    for(int p = 0; p < 2; ++p){
      gll16(msrc + wid*2048 + p*1024 + lane*16, &M[wid*2048 + p*1024]);
      gll16(gsrc + wid*2048 + p*1024 + lane*16, &G[wid*2048 + p*1024]);
    }
  }
  __syncthreads();                           // B1: M + G ready

  { // LN + gate-mul: 8 threads per j-row (16 d each); val -> G in place
    int j = tid >> 3, s = tid & 7;
    const int mrow = j*2;                    // byte base in M for this j
    float f0,f1,f2,f3,f4,f5,f6,f7,f8,f9,f10,f11,f12,f13,f14,f15;
#define RD(o) bf2f(*(const unsigned short*)(&M[mrow + (s*16 + (o))*64]))
    f0=RD(0); f1=RD(1); f2=RD(2); f3=RD(3); f4=RD(4); f5=RD(5); f6=RD(6); f7=RD(7);
    f8=RD(8); f9=RD(9); f10=RD(10); f11=RD(11); f12=RD(12); f13=RD(13); f14=RD(14); f15=RD(15);
#undef RD
    float sum = ((f0+f1)+(f2+f3)) + ((f4+f5)+(f6+f7))
              + ((f8+f9)+(f10+f11)) + ((f12+f13)+(f14+f15));
    float sq  = ((f0*f0+f1*f1)+(f2*f2+f3*f3)) + ((f4*f4+f5*f5)+(f6*f6+f7*f7))
              + ((f8*f8+f9*f9)+(f10*f10+f11*f11)) + ((f12*f12+f13*f13)+(f14*f14+f15*f15));
    sum += __shfl_xor(sum, 1); sq += __shfl_xor(sq, 1);
    sum += __shfl_xor(sum, 2); sq += __shfl_xor(sq, 2);
    sum += __shfl_xor(sum, 4); sq += __shfl_xor(sq, 4);
    float mean = sum*(1.f/128.f);
    float var  = sq *(1.f/128.f) - mean*mean;
    float rstd = rsqrtf(var + 1e-5f);
    float fv[16] = {f0,f1,f2,f3,f4,f5,f6,f7,f8,f9,f10,f11,f12,f13,f14,f15};
    #pragma unroll
    for(int o = 0; o < 16; o += 4){
      int dd = s*16 + o;
      char* gp = &G[j*256 + ((dd*2) ^ ((j&7)<<4))];
      uint2 gvv = *(uint2*)gp;
      float g0 = bf2f((unsigned short)(gvv.x & 0xffffu));
      float g1 = bf2f((unsigned short)(gvv.x >> 16));
      float g2 = bf2f((unsigned short)(gvv.y & 0xffffu));
      float g3 = bf2f((unsigned short)(gvv.y >> 16));
      float4 a4 = *(const float4*)(ona + dd);
      float4 b4 = *(const float4*)(onb + dd);
      float v0 = (a4.x*(fv[o  ]-mean)*rstd + b4.x)*g0;
      float v1 = (a4.y*(fv[o+1]-mean)*rstd + b4.y)*g1;
      float v2 = (a4.z*(fv[o+2]-mean)*rstd + b4.z)*g2;
      float v3 = (a4.w*(fv[o+3]-mean)*rstd + b4.w)*g3;
      uint2 pk; pk.x = cvtpk(v0, v1); pk.y = cvtpk(v2, v3);
      *(uint2*)gp = pk;                      // same thread RW: safe
    }
  }
  __syncthreads();                           // B2: val ready

  { // out MFMA: wave (wr=j-half, wc=c-half): 16 rows x 64 c
    const int wr = wid & 1, wc = wid >> 1;
    f32x4 zero = {0.f,0.f,0.f,0.f};
    f32x4 acc[4];
    #pragma unroll
    for(int fc = 0; fc < 4; ++fc) acc[fc] = zero;
    #pragma unroll
    for(int ks = 0; ks < 4; ++ks){
      int row = wr*16 + lrow;
      short8 a = *(const short8*)(&G[row*256 + (((ks*4+lgrp)*16) ^ ((row & 7) << 4))]);
      #pragma unroll
      for(int fc = 0; fc < 4; ++fc){
        short8 bfr = *(const short8*)(Wot + (wc*64 + fc*16 + lrow)*DD + ks*32 + lgrp*8);
        acc[fc] = mfma16(a, bfr, acc[fc]);
      }
    }
    #pragma unroll
    for(int fc = 0; fc < 4; ++fc){
      int c = wc*64 + fc*16 + lrow;
      float bb = bo[c];
      #pragma unroll
      for(int q = 0; q < 4; ++q){
        int jl = wr*16 + lgrp*4 + q;
        out[((long)i*NN + j0 + jl)*DD + c] = acc[fc][q] + bb;
      }
    }
  }
}

// ---------------------------------------------------------------------------
extern "C" void kernel_launch(void* const* d_in, const int* in_sizes, int n_in,
                              void* d_out, int out_size, void* d_ws, size_t ws_size,
                              hipStream_t stream){
  const float* x   = (const float*)d_in[0];
  const float* na  = (const float*)d_in[1];
  const float* nb  = (const float*)d_in[2];
  const float* Wl  = (const float*)d_in[3];
  const float* bl  = (const float*)d_in[4];
  const float* Wr  = (const float*)d_in[5];
  const float* br  = (const float*)d_in[6];
  const float* Wlg = (const float*)d_in[7];
  const float* blg = (const float*)d_in[8];
  const float* Wrg = (const float*)d_in[9];
  const float* brg = (const float*)d_in[10];
  const float* Wog = (const float*)d_in[11];
  const float* bog = (const float*)d_in[12];
  const float* ona = (const float*)d_in[13];
  const float* onb = (const float*)d_in[14];
  const float* Wo  = (const float*)d_in[15];
  const float* bo  = (const float*)d_in[16];
  float* out = (float*)d_out;

  char* ws = (char*)d_ws;
  const size_t SZ = (size_t)MM*DD*2;                    // 37.75 MB
  unsigned short* xn   = (unsigned short*)(ws);         // dead after k_proj
  unsigned short* Lt   = (unsigned short*)(ws + SZ);
  unsigned short* Rt   = (unsigned short*)(ws + 2*SZ);
  unsigned short* gate = (unsigned short*)(ws + 3*SZ);  // k_lng -> k_final
  unsigned short* Wcat = (unsigned short*)(ws + 4*SZ);
  unsigned short* Wot  = (unsigned short*)(ws + 4*SZ + (size_t)640*128*2);
  unsigned short* mid  = xn;                            // overlay (xn dead)

  k_prep  <<<768, 64, 0, stream>>>(Wl, Wlg, Wr, Wrg, Wog, Wo, Wcat, Wot);
  k_lng   <<<2304, 256, 0, stream>>>(x, na, nb, Wcat, bog, xn, gate);
  k_proj  <<<1152, 256, 0, stream>>>(xn, Wcat, bl, blg, br, brg, Lt, Rt);
  k_einsum<<<1152, 256, 0, stream>>>(Rt, Lt, mid);
  k_final <<<4608, 256, 0, stream>>>(mid, gate, ona, onb, Wot, bo, out);
}